// Round 1
// baseline (440.162 us; speedup 1.0000x reference)
//
#include <hip/hip_runtime.h>

// ---------------- constants ----------------
#define BB    4
#define SS    4096
#define HH    2048
#define NHH   4
#define HDD   512
#define NQQ   18
#define KMEM  16
#define FFND  4096
#define MAXE  128
#define QH    72          // NQ*NH flattened (qh = h*18 + qq)
#define QHP   80          // padded to MFMA multiple
#define SCALE_F 0.044194173824159216f   // 1/sqrt(512)

// output regions (f32 elements)
#define OUT_MEM     0
#define OUT_PRI     131072
#define OUT_CONF    131136
#define OUT_VAL     131140
#define OUT_ENT     131144
#define OUT_NEWPRI  393288

typedef float  f32x4  __attribute__((ext_vector_type(4)));
typedef __bf16 bf16x8 __attribute__((ext_vector_type(8)));

#define DEVFN static __device__ __forceinline__

DEVFN unsigned f2b(float f){            // f32 -> bf16 bits, RNE
  unsigned u = __builtin_bit_cast(unsigned, f);
  return (u + 0x7fffu + ((u >> 16) & 1u)) >> 16;
}
DEVFN bf16x8 pack8(f32x4 lo, f32x4 hi){
  uint4 u;
  u.x = f2b(lo[0]) | (f2b(lo[1]) << 16);
  u.y = f2b(lo[2]) | (f2b(lo[3]) << 16);
  u.z = f2b(hi[0]) | (f2b(hi[1]) << 16);
  u.w = f2b(hi[2]) | (f2b(hi[3]) << 16);
  return __builtin_bit_cast(bf16x8, u);
}
DEVFN bf16x8 pack8v(const float* v){
  uint4 u;
  u.x = f2b(v[0]) | (f2b(v[1]) << 16);
  u.y = f2b(v[2]) | (f2b(v[3]) << 16);
  u.z = f2b(v[4]) | (f2b(v[5]) << 16);
  u.w = f2b(v[6]) | (f2b(v[7]) << 16);
  return __builtin_bit_cast(bf16x8, u);
}
DEVFN float siluf(float x){ return x / (1.f + expf(-x)); }
DEVFN float block_sum(float v, float* sb){   // 256 threads
  #pragma unroll
  for (int o = 32; o > 0; o >>= 1) v += __shfl_xor(v, o);
  int wid = threadIdx.x >> 6, lane = threadIdx.x & 63;
  if (lane == 0) sb[wid] = v;
  __syncthreads();
  v = sb[0] + sb[1] + sb[2] + sb[3];
  __syncthreads();
  return v;
}

// ============ MFMA kernel 1: C(MP,N) += A_bf16(MP,Kf) @ Bt_f32(N,Kf)^T ============
// grid: (N/64, ksplit, batch); block 256. wave w owns n-frag n0=bx*64+w*16; MF m-frags.
template<int MF>
__global__ __launch_bounds__(256) void mfma_bt(
    const unsigned short* __restrict__ A, long aBatch,
    const float* __restrict__ Bt, long bBatch,
    float* __restrict__ C, long cBatch,
    int N, int Kf, int kcCount)
{
  int lane = threadIdx.x & 63, w = threadIdx.x >> 6;
  int z = blockIdx.z;
  int n0 = blockIdx.x * 64 + w * 16;
  int k0 = blockIdx.y * kcCount * 32;
  const unsigned short* aBase = A + z * aBatch + (long)(lane & 15) * Kf + k0 + 8 * (lane >> 4);
  const float* bBase = Bt + z * bBatch + (long)(n0 + (lane & 15)) * Kf + k0 + 8 * (lane >> 4);
  f32x4 acc[MF];
  #pragma unroll
  for (int m = 0; m < MF; m++) acc[m] = (f32x4)(0.f);
  for (int c = 0; c < kcCount; c++){
    f32x4 lo = *reinterpret_cast<const f32x4*>(bBase + c * 32);
    f32x4 hi = *reinterpret_cast<const f32x4*>(bBase + c * 32 + 4);
    bf16x8 bb = pack8(lo, hi);
    #pragma unroll
    for (int m = 0; m < MF; m++){
      bf16x8 aa = *reinterpret_cast<const bf16x8*>(aBase + (long)m * 16 * Kf + c * 32);
      acc[m] = __builtin_amdgcn_mfma_f32_16x16x32_bf16(aa, bb, acc[m], 0, 0, 0);
    }
  }
  int row0 = 4 * (lane >> 4);
  int col  = n0 + (lane & 15);
  #pragma unroll
  for (int m = 0; m < MF; m++)
    #pragma unroll
    for (int r = 0; r < 4; r++)
      atomicAdd(C + z * cBatch + (long)(m * 16 + row0 + r) * N + col, acc[m][r]);
}

// ==== MFMA kernel 2: C(80,N) += A_bf16(80,aRow) @ Bn_f32(K,N)  (B natural, strided) ====
__global__ __launch_bounds__(256) void mfma_abnat(
    const unsigned short* __restrict__ A, long aBatch, int aRow,
    const float* __restrict__ Bn, long bBatch,
    float* __restrict__ C, long cBatch,
    int N, int kcCount)
{
  int lane = threadIdx.x & 63, w = threadIdx.x >> 6;
  int z = blockIdx.z;
  int n0 = blockIdx.x * 64 + w * 16;
  int k0 = blockIdx.y * kcCount * 32;
  const unsigned short* aBase = A + z * aBatch + (long)(lane & 15) * aRow + k0 + 8 * (lane >> 4);
  const float* bBase = Bn + z * bBatch + (long)(k0 + 8 * (lane >> 4)) * N + n0 + (lane & 15);
  f32x4 acc[5];
  #pragma unroll
  for (int m = 0; m < 5; m++) acc[m] = (f32x4)(0.f);
  for (int c = 0; c < kcCount; c++){
    float v[8];
    const float* bp = bBase + (long)c * 32 * N;
    #pragma unroll
    for (int j = 0; j < 8; j++) v[j] = bp[(long)j * N];
    bf16x8 bb = pack8v(v);
    #pragma unroll
    for (int m = 0; m < 5; m++){
      bf16x8 aa = *reinterpret_cast<const bf16x8*>(aBase + (long)m * 16 * aRow + c * 32);
      acc[m] = __builtin_amdgcn_mfma_f32_16x16x32_bf16(aa, bb, acc[m], 0, 0, 0);
    }
  }
  int row0 = 4 * (lane >> 4);
  int col  = n0 + (lane & 15);
  #pragma unroll
  for (int m = 0; m < 5; m++)
    #pragma unroll
    for (int r = 0; r < 4; r++)
      atomicAdd(C + z * cBatch + (long)(m * 16 + row0 + r) * N + col, acc[m][r]);
}

// ==== MFMA kernel 3 (pass1): scores(s,qh) += hs_f32(s,H) @ qk_bf16(80,H)^T ====
// grid: (S/64, ksplit, b). wave w owns m-frag (16 s-rows); 5 n-frags cover 80 qh.
__global__ __launch_bounds__(256) void mfma_pass1(
    const float* __restrict__ hs, const unsigned short* __restrict__ qk,
    float* __restrict__ scores, int kcCount)
{
  int lane = threadIdx.x & 63, w = threadIdx.x >> 6;
  int b = blockIdx.z;
  int s0 = blockIdx.x * 64 + w * 16;
  int k0 = blockIdx.y * kcCount * 32;
  const float* aBase = hs + ((long)b * SS + s0 + (lane & 15)) * HH + k0 + 8 * (lane >> 4);
  const unsigned short* bBase = qk + (long)(lane & 15) * HH + k0 + 8 * (lane >> 4);
  f32x4 acc[5];
  #pragma unroll
  for (int n = 0; n < 5; n++) acc[n] = (f32x4)(0.f);
  for (int c = 0; c < kcCount; c++){
    f32x4 lo = *reinterpret_cast<const f32x4*>(aBase + c * 32);
    f32x4 hi = *reinterpret_cast<const f32x4*>(aBase + c * 32 + 4);
    bf16x8 aa = pack8(lo, hi);
    #pragma unroll
    for (int n = 0; n < 5; n++){
      bf16x8 bb = *reinterpret_cast<const bf16x8*>(bBase + (long)n * 16 * HH + c * 32);
      acc[n] = __builtin_amdgcn_mfma_f32_16x16x32_bf16(aa, bb, acc[n], 0, 0, 0);
    }
  }
  int row0 = s0 + 4 * (lane >> 4);
  #pragma unroll
  for (int n = 0; n < 5; n++)
    #pragma unroll
    for (int r = 0; r < 4; r++)
      atomicAdd(scores + ((long)b * SS + row0 + r) * QHP + n * 16 + (lane & 15), acc[n][r]);
}

// ==== VALU skinny GEMM: C(4,N) += A_f32(4,Kf) @ Bt_f32(N,Kf)^T (A scalar-loaded) ====
__global__ __launch_bounds__(256) void valu_bt(
    const float* __restrict__ A, const float* __restrict__ Bt,
    float* __restrict__ C, int N, int Kf, int kc)
{
  int n = blockIdx.x * 256 + threadIdx.x;
  int k0 = blockIdx.y * kc;
  const float* bp = Bt + (long)n * Kf + k0;
  float a0 = 0.f, a1 = 0.f, a2 = 0.f, a3 = 0.f;
  for (int k = 0; k < kc; k += 4){
    f32x4 bv = *reinterpret_cast<const f32x4*>(bp + k);
    #pragma unroll
    for (int j = 0; j < 4; j++){
      float b = bv[j];
      int ki = k0 + k + j;
      a0 += A[0 * Kf + ki] * b;
      a1 += A[1 * Kf + ki] * b;
      a2 += A[2 * Kf + ki] * b;
      a3 += A[3 * Kf + ki] * b;
    }
  }
  atomicAdd(&C[0 * N + n], a0);
  atomicAdd(&C[1 * N + n], a1);
  atomicAdd(&C[2 * N + n], a2);
  atomicAdd(&C[3 * N + n], a3);
}

// ---------------- small kernels ----------------
__global__ void k_prep_qA(const float* __restrict__ queries, unsigned short* __restrict__ qA){
  int i = blockIdx.x * 256 + threadIdx.x;       // 32*2048
  int r = i >> 11;
  float v = (r < NQQ) ? queries[i] : 0.f;
  qA[i] = (unsigned short)f2b(v);
}
__global__ void k_prep_Q2(const float* __restrict__ qf, unsigned short* __restrict__ Q2){
  int i = blockIdx.x * 256 + threadIdx.x;       // 80*2048
  int qh = i >> 11, e = i & 2047;
  float v = 0.f;
  if (qh < QH){
    int h = qh / NQQ, qq = qh % NQQ;
    if ((e >> 9) == h) v = qf[qq * HH + e] * SCALE_F;
  }
  Q2[i] = (unsigned short)f2b(v);
}
__global__ void k_cvt(const float* __restrict__ s, unsigned short* __restrict__ d){
  int i = blockIdx.x * 256 + threadIdx.x;
  d[i] = (unsigned short)f2b(s[i]);
}
__global__ __launch_bounds__(256) void k_softmax(const float* __restrict__ scores, unsigned short* __restrict__ attn){
  int qh = blockIdx.x, b = blockIdx.y;
  unsigned short* arow = attn + (long)(b * QHP + qh) * SS;
  if (qh >= QH){
    #pragma unroll
    for (int it = 0; it < 16; it++) arow[threadIdx.x + 256 * it] = 0;
    return;
  }
  const float* srow = scores + (long)b * SS * QHP + qh;
  float x[16]; float mx = -1e30f;
  #pragma unroll
  for (int it = 0; it < 16; it++){
    x[it] = srow[(long)(threadIdx.x + 256 * it) * QHP];
    mx = fmaxf(mx, x[it]);
  }
  __shared__ float sb[8];
  #pragma unroll
  for (int o = 32; o > 0; o >>= 1) mx = fmaxf(mx, __shfl_xor(mx, o));
  int wid = threadIdx.x >> 6, lane = threadIdx.x & 63;
  if (lane == 0) sb[wid] = mx;
  __syncthreads();
  mx = fmaxf(fmaxf(sb[0], sb[1]), fmaxf(sb[2], sb[3]));
  float sum = 0.f;
  #pragma unroll
  for (int it = 0; it < 16; it++){ x[it] = expf(x[it] - mx); sum += x[it]; }
  #pragma unroll
  for (int o = 32; o > 0; o >>= 1) sum += __shfl_xor(sum, o);
  if (lane == 0) sb[4 + wid] = sum;
  __syncthreads();
  sum = sb[4] + sb[5] + sb[6] + sb[7];
  float inv = 1.f / sum;
  #pragma unroll
  for (int it = 0; it < 16; it++) arow[threadIdx.x + 256 * it] = (unsigned short)f2b(x[it] * inv);
}
__global__ void k_pack_wv(const float* __restrict__ weighted, unsigned short* __restrict__ Apack){
  int i = blockIdx.x * 256 + threadIdx.x;       // 4*80*2048
  int h = i / (QHP * HH);
  int r = (i / HH) % QHP;
  int e = i & 2047;
  float v = 0.f;
  if (r < QH){
    int b = r / NQQ, qq = r % NQQ;
    v = weighted[((long)b * QHP + h * NQQ + qq) * HH + e];
  }
  Apack[i] = (unsigned short)f2b(v);
}
__global__ void k_pack_outB(const float* __restrict__ outv, unsigned short* __restrict__ outB){
  int i = blockIdx.x * 256 + threadIdx.x;       // 80*2048
  int r = i >> 11, c = i & 2047;
  int h = c >> 9, d = c & 511;
  float v = (r < QH) ? outv[((long)h * QHP + r) * HDD + d] : 0.f;
  outB[i] = (unsigned short)f2b(v);
}
__global__ __launch_bounds__(256) void k_rms(const float* __restrict__ extracted, const float* __restrict__ ln_w,
                                             unsigned short* __restrict__ xnb){
  int r = blockIdx.x;                            // 0..79
  unsigned short* dst = xnb + (long)r * HH;
  if (r >= 64){
    for (int i = threadIdx.x; i < HH; i += 256) dst[i] = 0;
    return;
  }
  int b = r >> 4, qq = r & 15;
  const float* src = extracted + (long)(b * NQQ + qq) * HH;
  __shared__ float sb[4];
  float xv[8]; float ss = 0.f;
  #pragma unroll
  for (int it = 0; it < 8; it++){
    xv[it] = src[threadIdx.x + 256 * it];
    ss += xv[it] * xv[it];
  }
  ss = block_sum(ss, sb);
  float inv = 1.f / sqrtf(ss * (1.f / 2048.f) + 1e-6f);
  #pragma unroll
  for (int it = 0; it < 8; it++){
    int e = threadIdx.x + 256 * it;
    dst[e] = (unsigned short)f2b(xv[it] * inv * ln_w[e]);
  }
}
__global__ void k_act(const float* __restrict__ gate, const float* __restrict__ up, unsigned short* __restrict__ hb){
  int i = blockIdx.x * 256 + threadIdx.x;       // 80*4096
  hb[i] = (unsigned short)f2b(siluf(gate[i]) * up[i]);
}
__global__ void k_memory(const float* __restrict__ extracted, const float* __restrict__ ffn, float* __restrict__ out){
  int i = blockIdx.x * 256 + threadIdx.x;       // 4*16*2048
  int b = i >> 15;
  int qq = (i >> 11) & 15;
  int e = i & 2047;
  out[OUT_MEM + i] = extracted[(long)(b * NQQ + qq) * HH + e] + ffn[i];
}
__global__ __launch_bounds__(256) void k_priority(const float* __restrict__ out_ro, const float* __restrict__ Wp,
                                                  const float* __restrict__ bp, float* __restrict__ out){
  __shared__ float sb[4];
  int row = blockIdx.x;                          // 0..63
  const float* m = out_ro + OUT_MEM + (long)row * HH;
  float v = 0.f;
  #pragma unroll
  for (int it = 0; it < 8; it++){ int e = threadIdx.x + 256 * it; v += m[e] * Wp[e]; }
  v = block_sum(v, sb);
  if (threadIdx.x == 0) out[OUT_PRI + row] = 1.f / (1.f + expf(-(v + bp[0])));
}
__global__ __launch_bounds__(256) void k_conf(const float* __restrict__ extracted, const float* __restrict__ Wh,
                                              const float* __restrict__ bh, float* __restrict__ out){
  __shared__ float sb[4];
  int b = blockIdx.x;
  const float* m = extracted + (long)(b * NQQ + 16) * HH;
  float v = 0.f;
  #pragma unroll
  for (int it = 0; it < 8; it++){ int e = threadIdx.x + 256 * it; v += m[e] * Wh[e]; }
  v = block_sum(v, sb);
  if (threadIdx.x == 0) out[OUT_CONF + b] = 1.f / (1.f + expf(-(v + bh[0])));
}
__global__ void k_vi(const float* __restrict__ extracted, const float* __restrict__ hs, float* __restrict__ vi){
  int i = blockIdx.x * 256 + threadIdx.x;       // 4*4096
  int b = i >> 12, c = i & 4095;
  vi[i] = (c < HH) ? extracted[(long)(b * NQQ + 17) * HH + c]
                   : hs[((long)b * SS + (SS - 1)) * HH + (c - HH)];
}
__global__ void k_h1act(const float* __restrict__ h1f, const float* __restrict__ b1, float* __restrict__ h1s){
  int i = blockIdx.x * 256 + threadIdx.x;       // 4*2048
  h1s[i] = siluf(h1f[i] + b1[i & 2047]);
}
__global__ __launch_bounds__(256) void k_value(const float* __restrict__ h2f, const float* __restrict__ b2,
                                               const float* __restrict__ V3, const float* __restrict__ b3,
                                               float* __restrict__ out){
  __shared__ float sb[4];
  int b = blockIdx.x;
  float v = 0.f;
  #pragma unroll
  for (int it = 0; it < 2; it++){
    int j = threadIdx.x + 256 * it;
    float t = h2f[b * HDD + j] + b2[j];
    v += siluf(t) * V3[j];
  }
  v = block_sum(v, sb);
  if (threadIdx.x == 0) out[OUT_VAL + b] = v + b3[0];
}
// exact sequential scan (16 steps) — single wave, first-occurrence argmin
__global__ void k_scan(const float* __restrict__ buf_pri, const float* __restrict__ out_ro,
                       float* __restrict__ out, int* __restrict__ tw){
  int lane = threadIdx.x;                        // 64 threads
  float pr0 = buf_pri[lane], pr1 = buf_pri[lane + 64];
  int tw0 = -1, tw1 = -1;
  for (int i = 0; i < 16; i++){
    float p = out_ro[OUT_PRI + i];               // priority[0][i]
    float v; int idx;
    if (pr0 <= pr1){ v = pr0; idx = lane; } else { v = pr1; idx = lane + 64; }
    #pragma unroll
    for (int o = 32; o > 0; o >>= 1){
      float ov = __shfl_xor(v, o);
      int   oi = __shfl_xor(idx, o);
      if (ov < v || (ov == v && oi < idx)){ v = ov; idx = oi; }
    }
    if (p > v){
      if (idx == lane)          { pr0 = p; tw0 = i; }
      else if (idx == lane + 64){ pr1 = p; tw1 = i; }
    }
  }
  out[OUT_NEWPRI + lane]      = pr0;
  out[OUT_NEWPRI + lane + 64] = pr1;
  tw[lane] = tw0; tw[lane + 64] = tw1;
}
__global__ void k_entries(const float* __restrict__ buf_ent, const float* __restrict__ out_ro,
                          const int* __restrict__ tw, float* __restrict__ out){
  int row = blockIdx.x;                          // 0..127
  int t = tw[row];
  const f32x4* s = reinterpret_cast<const f32x4*>(
      (t < 0) ? (buf_ent + (long)row * HH) : (out_ro + OUT_MEM + (long)t * HH));
  f32x4* d = reinterpret_cast<f32x4*>(out + OUT_ENT + (long)row * HH);
  for (int i = threadIdx.x; i < HH / 4; i += 256) d[i] = s[i];
}

// ---------------- launcher ----------------
extern "C" void kernel_launch(void* const* d_in, const int* in_sizes, int n_in,
                              void* d_out, int out_size, void* d_ws, size_t ws_size,
                              hipStream_t stream)
{
  const float* hs      = (const float*)d_in[0];
  const float* buf_ent = (const float*)d_in[1];
  const float* buf_pri = (const float*)d_in[2];
  const float* queries = (const float*)d_in[3];
  const float* Wq  = (const float*)d_in[4];
  const float* Wk  = (const float*)d_in[5];
  const float* Wv  = (const float*)d_in[6];
  const float* Wo  = (const float*)d_in[7];
  const float* ln_w= (const float*)d_in[8];
  const float* Wgate=(const float*)d_in[9];
  const float* Wup = (const float*)d_in[10];
  const float* Wdown=(const float*)d_in[11];
  const float* Wp  = (const float*)d_in[12];
  const float* bp  = (const float*)d_in[13];
  const float* Wh  = (const float*)d_in[14];
  const float* bh  = (const float*)d_in[15];
  const float* V1  = (const float*)d_in[16];
  const float* b1  = (const float*)d_in[17];
  const float* V2  = (const float*)d_in[18];
  const float* b2  = (const float*)d_in[19];
  const float* V3  = (const float*)d_in[20];
  const float* b3  = (const float*)d_in[21];
  float* out = (float*)d_out;
  char* ws = (char*)d_ws;

  // ---- workspace layout (all offsets 256B-aligned) ----
  // Z-zone (zeroed each call; atomicAdd targets)
  float* q_f32     = (float*)(ws + 0);          //  32*2048
  float* qk_f32    = (float*)(ws + 262144);     //  80*2048
  float* scores    = (float*)(ws + 917504);     //  4*4096*80
  float* weighted  = (float*)(ws + 6160384);    //  4*80*2048
  float* outv      = (float*)(ws + 8781824);    //  4*80*512
  float* extracted = (float*)(ws + 9437184);    //  80*2048
  float* gate      = (float*)(ws + 10092544);   //  80*4096
  float* up        = (float*)(ws + 11403264);   //  80*4096
  float* ffn       = (float*)(ws + 12713984);   //  80*2048
  float* h1f       = (float*)(ws + 13369344);   //  4*2048
  float* h2f       = (float*)(ws + 13402112);   //  4*512
  const size_t ZBYTES = 13410304;
  // NZ zone (fully overwritten each call)
  unsigned short* qA    = (unsigned short*)(ws + 13410304);  // 32*2048
  unsigned short* Q2    = (unsigned short*)(ws + 13541376);  // 80*2048
  unsigned short* qk_bf = (unsigned short*)(ws + 13869056);  // 80*2048
  unsigned short* attn  = (unsigned short*)(ws + 14196736);  // 4*80*4096
  unsigned short* Apack = (unsigned short*)(ws + 16818176);  // 4*80*2048
  unsigned short* outB  = (unsigned short*)(ws + 18128896);  // 80*2048
  unsigned short* xnb   = (unsigned short*)(ws + 18456576);  // 80*2048
  unsigned short* hb    = (unsigned short*)(ws + 18784256);  // 80*4096
  float* h1s            = (float*)(ws + 19439616);           // 4*2048
  float* vi             = (float*)(ws + 19472384);           // 4*4096
  int*   tw             = (int*)  (ws + 19537920);           // 128

  hipMemsetAsync(d_ws, 0, ZBYTES, stream);

  // q = queries @ Wq.T   (pad M 18->32)
  k_prep_qA<<<256, 256, 0, stream>>>(queries, qA);
  mfma_bt<2><<<dim3(32, 4, 1), 256, 0, stream>>>(qA, 0, Wq, 0, q_f32, 0, 2048, 2048, 16);
  // qk = Q2 @ Wk  (Q2 = scaled, head-masked q, 80x2048)
  k_prep_Q2<<<640, 256, 0, stream>>>(q_f32, Q2);
  mfma_abnat<<<dim3(32, 4, 1), 256, 0, stream>>>(Q2, 0, 2048, Wk, 0, qk_f32, 0, 2048, 16);
  k_cvt<<<640, 256, 0, stream>>>(qk_f32, qk_bf);
  // pass1: scores[b][s][qh] = hs @ qk^T   (128 MB hs read)
  mfma_pass1<<<dim3(64, 2, 4), 256, 0, stream>>>(hs, qk_bf, scores, 32);
  // softmax over s -> attn bf16 [b][qh][s]
  k_softmax<<<dim3(80, 4), 256, 0, stream>>>(scores, attn);
  // pass3: weighted[b][qh][e] = attn @ hs   (128 MB hs read)
  mfma_abnat<<<dim3(32, 8, 4), 256, 0, stream>>>(attn, 80L * 4096, 4096, hs, (long)SS * HH,
                                                 weighted, 80L * 2048, 2048, 16);
  // per-head V projection: outv[h] = Apack[h] @ Wv_h^T
  k_pack_wv<<<2560, 256, 0, stream>>>(weighted, Apack);
  mfma_bt<5><<<dim3(8, 4, 4), 256, 0, stream>>>(Apack, 80L * 2048, Wv, 512L * 2048,
                                                outv, 80L * 512, 512, 2048, 16);
  // O projection: extracted = outB @ Wo^T
  k_pack_outB<<<640, 256, 0, stream>>>(outv, outB);
  mfma_bt<5><<<dim3(32, 4, 1), 256, 0, stream>>>(outB, 0, Wo, 0, extracted, 0, 2048, 2048, 16);
  // RMSNorm + FFN (SwiGLU)
  k_rms<<<80, 256, 0, stream>>>(extracted, ln_w, xnb);
  mfma_bt<5><<<dim3(64, 4, 1), 256, 0, stream>>>(xnb, 0, Wgate, 0, gate, 0, 4096, 2048, 16);
  mfma_bt<5><<<dim3(64, 4, 1), 256, 0, stream>>>(xnb, 0, Wup, 0, up, 0, 4096, 2048, 16);
  k_act<<<1280, 256, 0, stream>>>(gate, up, hb);
  mfma_bt<5><<<dim3(32, 8, 1), 256, 0, stream>>>(hb, 0, Wdown, 0, ffn, 0, 2048, 4096, 16);
  // memory = memory_raw + ffn  -> d_out
  k_memory<<<512, 256, 0, stream>>>(extracted, ffn, out);
  // heads
  k_priority<<<64, 256, 0, stream>>>(out, Wp, bp, out);
  k_conf<<<4, 256, 0, stream>>>(extracted, Wh, bh, out);
  // value MLP
  k_vi<<<64, 256, 0, stream>>>(extracted, hs, vi);
  valu_bt<<<dim3(8, 16), 256, 0, stream>>>(vi, V1, h1f, 2048, 4096, 256);
  k_h1act<<<32, 256, 0, stream>>>(h1f, b1, h1s);
  valu_bt<<<dim3(2, 8), 256, 0, stream>>>(h1s, V2, h2f, 512, 2048, 256);
  k_value<<<4, 256, 0, stream>>>(h2f, b2, V3, b3, out);
  // buffer scan + entry writes
  k_scan<<<1, 64, 0, stream>>>(buf_pri, out, out, tw);
  k_entries<<<128, 256, 0, stream>>>(buf_ent, out, tw, out);
}

// Round 2
// 313.195 us; speedup vs baseline: 1.4054x; 1.4054x over previous
//
#include <hip/hip_runtime.h>

// ---------------- constants ----------------
#define SS    4096
#define HH    2048
#define NQQ   18
#define QH    72
#define SCALE_F 0.044194173824159216f   // 1/sqrt(512)

// output regions (f32 elements)
#define OUT_MEM     0
#define OUT_PRI     131072
#define OUT_CONF    131136
#define OUT_VAL     131140
#define OUT_ENT     131144
#define OUT_NEWPRI  393288

typedef float  f32x4  __attribute__((ext_vector_type(4)));
typedef __bf16 bf16x8 __attribute__((ext_vector_type(8)));

#define DEVFN static __device__ __forceinline__

DEVFN bf16x8 pack8(f32x4 lo, f32x4 hi){
  bf16x8 r;
  #pragma unroll
  for (int i = 0; i < 4; i++){ r[i] = (__bf16)lo[i]; r[i+4] = (__bf16)hi[i]; }
  return r;
}
DEVFN float siluf(float x){ return x / (1.f + expf(-x)); }
DEVFN float block_sum(float v, float* sb){   // 256 threads
  #pragma unroll
  for (int o = 32; o > 0; o >>= 1) v += __shfl_xor(v, o);
  int wid = threadIdx.x >> 6, lane = threadIdx.x & 63;
  if (lane == 0) sb[wid] = v;
  __syncthreads();
  v = sb[0] + sb[1] + sb[2] + sb[3];
  __syncthreads();
  return v;
}

// ======== GEMM-BT: Cp[y][Mp][N] = A_bf16(Mp,Kf) @ B_f32(N,Kf)^T (K-chunk y) ========
// grid (N/64, Kf/(32*KC), Z). Z=2 selects (B1,C1). HSEL: A block by output head (n0>>9).
template<int MF, int KC, bool HSEL>
__global__ __launch_bounds__(256) void gemm_bt(
    const __bf16* __restrict__ A, int Kf,
    const float* __restrict__ B0, float* __restrict__ C0,
    const float* __restrict__ B1, float* __restrict__ C1,
    int N)
{
  constexpr int Mp = 16 * MF;
  const int lane = threadIdx.x & 63, w = threadIdx.x >> 6;
  const int n0 = blockIdx.x * 64 + w * 16;
  const int k0 = blockIdx.y * KC * 32;
  const float* B = blockIdx.z ? B1 : B0;
  float* Cp      = blockIdx.z ? C1 : C0;
  const __bf16* aBase = A + (HSEL ? (long)(n0 >> 9) * Mp * Kf : 0)
                          + (long)(lane & 15) * Kf + k0 + 8 * (lane >> 4);
  const float* bBase = B + (long)(n0 + (lane & 15)) * Kf + k0 + 8 * (lane >> 4);
  f32x4 acc[MF];
  #pragma unroll
  for (int m = 0; m < MF; m++) acc[m] = (f32x4)(0.f);
  #pragma unroll 4
  for (int c = 0; c < KC; c++){
    f32x4 lo = *reinterpret_cast<const f32x4*>(bBase + c * 32);
    f32x4 hi = *reinterpret_cast<const f32x4*>(bBase + c * 32 + 4);
    bf16x8 bb = pack8(lo, hi);
    #pragma unroll
    for (int m = 0; m < MF; m++){
      bf16x8 aa = *reinterpret_cast<const bf16x8*>(aBase + (long)m * 16 * Kf + c * 32);
      acc[m] = __builtin_amdgcn_mfma_f32_16x16x32_bf16(aa, bb, acc[m], 0, 0, 0);
    }
  }
  float* cp = Cp + (long)blockIdx.y * Mp * N;
  int row0 = 4 * (lane >> 4), col = n0 + (lane & 15);
  #pragma unroll
  for (int m = 0; m < MF; m++)
    #pragma unroll
    for (int r = 0; r < 4; r++)
      cp[(long)(m * 16 + row0 + r) * N + col] = acc[m][r];
}

// ======== GEMM-ABNAT: Cp[z][y][Mp][N] = A_bf16(z)(Mp,aStride) @ Bn_f32(z)(K,N) ========
template<int MF, int KC>
__global__ __launch_bounds__(256) void gemm_abnat(
    const __bf16* __restrict__ A, long aBatch, int aStride,
    const float* __restrict__ Bn, long bBatch,
    float* __restrict__ Cp, long cBatch,
    int N)
{
  constexpr int Mp = 16 * MF;
  const int lane = threadIdx.x & 63, w = threadIdx.x >> 6;
  const int z = blockIdx.z;
  const int n0 = blockIdx.x * 64 + w * 16;
  const int k0 = blockIdx.y * KC * 32;
  const __bf16* aBase = A + z * aBatch + (long)(lane & 15) * aStride + k0 + 8 * (lane >> 4);
  const float* bBase = Bn + z * bBatch + (long)(k0 + 8 * (lane >> 4)) * N + n0 + (lane & 15);
  f32x4 acc[MF];
  #pragma unroll
  for (int m = 0; m < MF; m++) acc[m] = (f32x4)(0.f);
  #pragma unroll 2
  for (int c = 0; c < KC; c++){
    const float* bp = bBase + (long)c * 32 * N;
    bf16x8 bb;
    #pragma unroll
    for (int j = 0; j < 8; j++) bb[j] = (__bf16)bp[(long)j * N];
    #pragma unroll
    for (int m = 0; m < MF; m++){
      bf16x8 aa = *reinterpret_cast<const bf16x8*>(aBase + (long)m * 16 * aStride + c * 32);
      acc[m] = __builtin_amdgcn_mfma_f32_16x16x32_bf16(aa, bb, acc[m], 0, 0, 0);
    }
  }
  float* cp = Cp + z * cBatch + (long)blockIdx.y * Mp * N;
  int row0 = 4 * (lane >> 4), col = n0 + (lane & 15);
  #pragma unroll
  for (int m = 0; m < MF; m++)
    #pragma unroll
    for (int r = 0; r < 4; r++)
      cp[(long)(m * 16 + row0 + r) * N + col] = acc[m][r];
}

// ======== pass1: Sp[y][b][qh][s] = hs(b)(s,H) @ qk_bf16(80,H)^T, transposed store ========
template<int KC>
__global__ __launch_bounds__(256) void gemm_pass1(
    const float* __restrict__ hs, const __bf16* __restrict__ qk,
    float* __restrict__ Sp)
{
  const int lane = threadIdx.x & 63, w = threadIdx.x >> 6;
  const int b = blockIdx.z;
  const int s0 = blockIdx.x * 64 + w * 16;
  const int k0 = blockIdx.y * KC * 32;
  const float* aBase = hs + ((long)b * SS + s0 + (lane & 15)) * HH + k0 + 8 * (lane >> 4);
  const __bf16* bBase = qk + (long)(lane & 15) * HH + k0 + 8 * (lane >> 4);
  f32x4 acc[5];
  #pragma unroll
  for (int n = 0; n < 5; n++) acc[n] = (f32x4)(0.f);
  #pragma unroll 4
  for (int c = 0; c < KC; c++){
    f32x4 lo = *reinterpret_cast<const f32x4*>(aBase + c * 32);
    f32x4 hi = *reinterpret_cast<const f32x4*>(aBase + c * 32 + 4);
    bf16x8 aa = pack8(lo, hi);
    #pragma unroll
    for (int n = 0; n < 5; n++){
      bf16x8 bb = *reinterpret_cast<const bf16x8*>(bBase + (long)n * 16 * HH + c * 32);
      acc[n] = __builtin_amdgcn_mfma_f32_16x16x32_bf16(aa, bb, acc[n], 0, 0, 0);
    }
  }
  float* sp = Sp + ((long)blockIdx.y * 4 + b) * 80 * SS;
  int scol = s0 + 4 * (lane >> 4);
  #pragma unroll
  for (int n = 0; n < 5; n++){
    int qh = n * 16 + (lane & 15);
    *reinterpret_cast<f32x4*>(sp + (long)qh * SS + scol) = acc[n];
  }
}

// ---------------- small / epilogue kernels ----------------
__global__ void k_prep_qA(const float* __restrict__ queries, __bf16* __restrict__ qA){
  int i = blockIdx.x * 256 + threadIdx.x;       // 32*2048
  int r = i >> 11;
  qA[i] = (__bf16)((r < NQQ) ? queries[i] : 0.f);
}
__global__ void k_mkQ2(const float* __restrict__ q_p, __bf16* __restrict__ Q2){
  int i = blockIdx.x * 256 + threadIdx.x;       // 80*2048
  int qh = i >> 11, e = i & 2047;
  float v = 0.f;
  if (qh < QH){
    int h = qh / NQQ, qq = qh - h * NQQ;
    if ((e >> 9) == h){
      float s = 0.f;
      #pragma unroll
      for (int y = 0; y < 8; y++) s += q_p[(long)y * 32 * 2048 + qq * 2048 + e];
      v = s * SCALE_F;
    }
  }
  Q2[i] = (__bf16)v;
}
__global__ void k_mkqk(const float* __restrict__ qk_p, __bf16* __restrict__ qk_bf){
  int i = blockIdx.x * 256 + threadIdx.x;       // 80*2048
  float s = 0.f;
  #pragma unroll
  for (int y = 0; y < 8; y++) s += qk_p[(long)y * 80 * 2048 + i];
  qk_bf[i] = (__bf16)s;
}
__global__ __launch_bounds__(256) void k_softmax(const float* __restrict__ Sp, __bf16* __restrict__ attn){
  int qh = blockIdx.x, b = blockIdx.y;
  __bf16* arow = attn + ((long)b * 80 + qh) * SS;
  if (qh >= QH){
    #pragma unroll
    for (int it = 0; it < 16; it++) arow[threadIdx.x + 256 * it] = (__bf16)0.f;
    return;
  }
  const float* r0 = Sp + ((long)b * 80 + qh) * SS;
  const float* r1 = r0 + (long)4 * 80 * SS;
  float x[16]; float mx = -1e30f;
  #pragma unroll
  for (int it = 0; it < 16; it++){
    int s = threadIdx.x + 256 * it;
    x[it] = r0[s] + r1[s];
    mx = fmaxf(mx, x[it]);
  }
  __shared__ float sb[8];
  #pragma unroll
  for (int o = 32; o > 0; o >>= 1) mx = fmaxf(mx, __shfl_xor(mx, o));
  int wid = threadIdx.x >> 6, lane = threadIdx.x & 63;
  if (lane == 0) sb[wid] = mx;
  __syncthreads();
  mx = fmaxf(fmaxf(sb[0], sb[1]), fmaxf(sb[2], sb[3]));
  float sum = 0.f;
  #pragma unroll
  for (int it = 0; it < 16; it++){ x[it] = expf(x[it] - mx); sum += x[it]; }
  #pragma unroll
  for (int o = 32; o > 0; o >>= 1) sum += __shfl_xor(sum, o);
  if (lane == 0) sb[4 + wid] = sum;
  __syncthreads();
  sum = sb[4] + sb[5] + sb[6] + sb[7];
  float inv = 1.f / sum;
  #pragma unroll
  for (int it = 0; it < 16; it++) arow[threadIdx.x + 256 * it] = (__bf16)(x[it] * inv);
}
__global__ void k_pack_wv(const float* __restrict__ w_p, __bf16* __restrict__ Apack){
  int i = blockIdx.x * 256 + threadIdx.x;       // 4*80*2048
  int h = i / (80 * 2048);
  int r = (i / 2048) % 80;
  int e = i & 2047;
  float v = 0.f;
  if (r < QH){
    int b = r / NQQ, qq = r - b * NQQ;
    const float* base = w_p + ((long)b * 4 * 80 + (h * NQQ + qq)) * 2048 + e;
    #pragma unroll
    for (int y = 0; y < 4; y++) v += base[(long)y * 80 * 2048];
  }
  Apack[i] = (__bf16)v;
}
__global__ void k_sum_outB(const float* __restrict__ outB_p, __bf16* __restrict__ outB){
  int i = blockIdx.x * 256 + threadIdx.x;       // 80*2048
  float s = 0.f;
  #pragma unroll
  for (int y = 0; y < 8; y++) s += outB_p[(long)y * 80 * 2048 + i];
  outB[i] = (__bf16)s;
}
__global__ __launch_bounds__(256) void k_rms(const float* __restrict__ ext_p, const float* __restrict__ ln_w,
                                             float* __restrict__ extracted, __bf16* __restrict__ xnb){
  int r = blockIdx.x;                            // 0..95
  if (r >= 80){                                  // zero xnb pad rows 64..79
    __bf16* dst = xnb + (long)(r - 16) * HH;
    for (int i = threadIdx.x; i < HH; i += 256) dst[i] = (__bf16)0.f;
    return;
  }
  float xv[8]; float ss = 0.f;
  #pragma unroll
  for (int it = 0; it < 8; it++){
    int e = threadIdx.x + 256 * it;
    float s = 0.f;
    #pragma unroll
    for (int y = 0; y < 8; y++) s += ext_p[((long)y * 80 + r) * 2048 + e];
    extracted[(long)r * 2048 + e] = s;
    xv[it] = s;
    ss += s * s;
  }
  int b = r / NQQ, qq = r - b * NQQ;
  if (r < QH && qq < 16){
    __shared__ float sb[4];
    ss = block_sum(ss, sb);
    float inv = 1.f / sqrtf(ss * (1.f / 2048.f) + 1e-6f);
    __bf16* dst = xnb + (long)(b * 16 + qq) * HH;
    #pragma unroll
    for (int it = 0; it < 8; it++){
      int e = threadIdx.x + 256 * it;
      dst[e] = (__bf16)(xv[it] * inv * ln_w[e]);
    }
  }
}
__global__ void k_vi_pack(const float* __restrict__ extracted, const float* __restrict__ hs,
                          __bf16* __restrict__ vi){
  int i = blockIdx.x * 256 + threadIdx.x;       // 16*4096
  int r = i >> 12, c = i & 4095;
  float v = 0.f;
  if (r < 4)
    v = (c < HH) ? extracted[(long)(r * NQQ + 17) * HH + c]
                 : hs[((long)r * SS + (SS - 1)) * HH + (c - HH)];
  vi[i] = (__bf16)v;
}
__global__ void k_act(const float* __restrict__ gate_p, const float* __restrict__ up_p,
                      __bf16* __restrict__ hb){
  int i = blockIdx.x * 256 + threadIdx.x;       // 80*4096
  float g = 0.f, u = 0.f;
  #pragma unroll
  for (int y = 0; y < 4; y++){
    g += gate_p[(long)y * 80 * 4096 + i];
    u += up_p[(long)y * 80 * 4096 + i];
  }
  hb[i] = (__bf16)(siluf(g) * u);
}
__global__ void k_h1act(const float* __restrict__ h1_p, const float* __restrict__ b1,
                        __bf16* __restrict__ h1s){
  int i = blockIdx.x * 256 + threadIdx.x;       // 16*2048
  int r = i >> 11, e = i & 2047;
  float v = 0.f;
  if (r < 4){
    float s = 0.f;
    #pragma unroll
    for (int y = 0; y < 16; y++) s += h1_p[(long)y * 16 * 2048 + i];
    v = siluf(s + b1[e]);
  }
  h1s[i] = (__bf16)v;
}
__global__ void k_memory(const float* __restrict__ extracted, const float* __restrict__ ffn_p,
                         float* __restrict__ out){
  int i = blockIdx.x * 256 + threadIdx.x;       // 4*16*2048
  int b = i >> 15, qq = (i >> 11) & 15, e = i & 2047;
  float f = 0.f;
  #pragma unroll
  for (int y = 0; y < 8; y++) f += ffn_p[((long)y * 80 + b * 16 + qq) * 2048 + e];
  out[OUT_MEM + i] = extracted[(long)(b * NQQ + qq) * HH + e] + f;
}
__global__ __launch_bounds__(256) void k_heads(
    const float* __restrict__ out_ro, const float* __restrict__ extracted,
    const float* __restrict__ h2_p,
    const float* __restrict__ Wp, const float* __restrict__ bp,
    const float* __restrict__ Wh, const float* __restrict__ bh,
    const float* __restrict__ b2, const float* __restrict__ V3, const float* __restrict__ b3,
    float* __restrict__ out)
{
  __shared__ float sb[4];
  int blk = blockIdx.x;                          // 0..71
  if (blk < 64){                                 // priority
    const float* m = out_ro + OUT_MEM + (long)blk * HH;
    float v = 0.f;
    #pragma unroll
    for (int it = 0; it < 8; it++){ int e = threadIdx.x + 256 * it; v += m[e] * Wp[e]; }
    v = block_sum(v, sb);
    if (threadIdx.x == 0) out[OUT_PRI + blk] = 1.f / (1.f + expf(-(v + bp[0])));
  } else if (blk < 68){                          // confidence
    int b = blk - 64;
    const float* m = extracted + (long)(b * NQQ + 16) * HH;
    float v = 0.f;
    #pragma unroll
    for (int it = 0; it < 8; it++){ int e = threadIdx.x + 256 * it; v += m[e] * Wh[e]; }
    v = block_sum(v, sb);
    if (threadIdx.x == 0) out[OUT_CONF + b] = 1.f / (1.f + expf(-(v + bh[0])));
  } else {                                       // value
    int b = blk - 68;
    float v = 0.f;
    #pragma unroll
    for (int it = 0; it < 2; it++){
      int j = threadIdx.x + 256 * it;
      float s = 0.f;
      #pragma unroll
      for (int y = 0; y < 8; y++) s += h2_p[(long)y * 16 * 512 + b * 512 + j];
      v += siluf(s + b2[j]) * V3[j];
    }
    v = block_sum(v, sb);
    if (threadIdx.x == 0) out[OUT_VAL + b] = v + b3[0];
  }
}
__global__ void k_scan(const float* __restrict__ buf_pri, const float* __restrict__ out_ro,
                       float* __restrict__ out, int* __restrict__ tw){
  int lane = threadIdx.x;                        // 64 threads
  float pr0 = buf_pri[lane], pr1 = buf_pri[lane + 64];
  int tw0 = -1, tw1 = -1;
  for (int i = 0; i < 16; i++){
    float p = out_ro[OUT_PRI + i];
    float v; int idx;
    if (pr0 <= pr1){ v = pr0; idx = lane; } else { v = pr1; idx = lane + 64; }
    #pragma unroll
    for (int o = 32; o > 0; o >>= 1){
      float ov = __shfl_xor(v, o);
      int   oi = __shfl_xor(idx, o);
      if (ov < v || (ov == v && oi < idx)){ v = ov; idx = oi; }
    }
    if (p > v){
      if (idx == lane)          { pr0 = p; tw0 = i; }
      else if (idx == lane + 64){ pr1 = p; tw1 = i; }
    }
  }
  out[OUT_NEWPRI + lane]      = pr0;
  out[OUT_NEWPRI + lane + 64] = pr1;
  tw[lane] = tw0; tw[lane + 64] = tw1;
}
__global__ void k_entries(const float* __restrict__ buf_ent, const float* __restrict__ out_ro,
                          const int* __restrict__ tw, float* __restrict__ out){
  int row = blockIdx.x;                          // 0..127
  int t = tw[row];
  const f32x4* s = reinterpret_cast<const f32x4*>(
      (t < 0) ? (buf_ent + (long)row * HH) : (out_ro + OUT_MEM + (long)t * HH));
  f32x4* d = reinterpret_cast<f32x4*>(out + OUT_ENT + (long)row * HH);
  #pragma unroll
  for (int i = 0; i < 2; i++) d[threadIdx.x + 256 * i] = s[threadIdx.x + 256 * i];
}

// ---------------- launcher ----------------
extern "C" void kernel_launch(void* const* d_in, const int* in_sizes, int n_in,
                              void* d_out, int out_size, void* d_ws, size_t ws_size,
                              hipStream_t stream)
{
  const float* hs      = (const float*)d_in[0];
  const float* buf_ent = (const float*)d_in[1];
  const float* buf_pri = (const float*)d_in[2];
  const float* queries = (const float*)d_in[3];
  const float* Wq  = (const float*)d_in[4];
  const float* Wk  = (const float*)d_in[5];
  const float* Wv  = (const float*)d_in[6];
  const float* Wo  = (const float*)d_in[7];
  const float* ln_w= (const float*)d_in[8];
  const float* Wgate=(const float*)d_in[9];
  const float* Wup = (const float*)d_in[10];
  const float* Wdown=(const float*)d_in[11];
  const float* Wp  = (const float*)d_in[12];
  const float* bp  = (const float*)d_in[13];
  const float* Wh  = (const float*)d_in[14];
  const float* bh  = (const float*)d_in[15];
  const float* V1  = (const float*)d_in[16];
  const float* b1  = (const float*)d_in[17];
  const float* V2  = (const float*)d_in[18];
  const float* b2  = (const float*)d_in[19];
  const float* V3  = (const float*)d_in[20];
  const float* b3  = (const float*)d_in[21];
  float* out = (float*)d_out;
  char* ws = (char*)d_ws;

  // ---- workspace (time-aliased regions; no memset, no atomics) ----
  // RegionA (10,485,760 B): scores_p -> w_p -> gate_p+up_p
  float* scores_p = (float*)(ws + 0);            // [2][4][80][4096]
  float* w_p      = (float*)(ws + 0);            // [4][4][80][2048]
  float* gate_p   = (float*)(ws + 0);            // [4][80][4096]
  float* up_p     = (float*)(ws + 5242880);      // [4][80][4096]
  // RegionB (5,242,880 B): q_p -> qk_p -> outB_p -> ext_p -> ffn_p
  float* q_p      = (float*)(ws + 10485760);     // [8][32][2048]
  float* qk_p     = (float*)(ws + 10485760);     // [8][80][2048]
  float* outB_p   = (float*)(ws + 10485760);     // [8][80][2048]
  float* ext_p    = (float*)(ws + 10485760);     // [8][80][2048]
  float* ffn_p    = (float*)(ws + 10485760);     // [8][80][2048]
  // persistents
  __bf16* qA    = (__bf16*)(ws + 15728640);      // 32*2048
  __bf16* Q2    = (__bf16*)(ws + 15859712);      // 80*2048
  __bf16* qk_bf = (__bf16*)(ws + 16187392);      // 80*2048
  __bf16* attn  = (__bf16*)(ws + 16515072);      // 4*80*4096
  __bf16* Apack = (__bf16*)(ws + 19136512);      // 4*80*2048
  __bf16* outB  = (__bf16*)(ws + 20447232);      // 80*2048
  float*  extracted = (float*)(ws + 20774912);   // 80*2048 f32
  __bf16* xnb   = (__bf16*)(ws + 21430272);      // 80*2048
  __bf16* hb    = (__bf16*)(ws + 21757952);      // 80*4096
  __bf16* vi    = (__bf16*)(ws + 22413312);      // 16*4096
  __bf16* h1s   = (__bf16*)(ws + 22544384);      // 16*2048
  float*  h1_p  = (float*)(ws + 22609920);       // [16][16][2048]
  float*  h2_p  = (float*)(ws + 24707072);       // [8][16][512]
  int*    tw    = (int*)  (ws + 24969216);       // 128

  // q = queries @ Wq^T
  k_prep_qA<<<256, 256, 0, stream>>>(queries, qA);
  gemm_bt<2, 8, false><<<dim3(32, 8, 1), 256, 0, stream>>>(qA, 2048, Wq, q_p, Wq, q_p, 2048);
  k_mkQ2<<<640, 256, 0, stream>>>(q_p, Q2);
  // qk = Q2 @ Wk
  gemm_abnat<5, 8><<<dim3(32, 8, 1), 256, 0, stream>>>(Q2, 0, 2048, Wk, 0, qk_p, 0, 2048);
  k_mkqk<<<640, 256, 0, stream>>>(qk_p, qk_bf);
  // pass1: scores_t[y][b][qh][s] = hs @ qk^T
  gemm_pass1<32><<<dim3(64, 2, 4), 256, 0, stream>>>(hs, qk_bf, scores_p);
  k_softmax<<<dim3(80, 4), 256, 0, stream>>>(scores_p, attn);
  // pass3: weighted = attn @ hs
  gemm_abnat<5, 32><<<dim3(32, 4, 4), 256, 0, stream>>>(attn, 80L * 4096, 4096,
      hs, (long)SS * HH, w_p, 4L * 80 * 2048, 2048);
  k_pack_wv<<<2560, 256, 0, stream>>>(w_p, Apack);
  // V projection (block-diag by head), output already in outB layout
  gemm_bt<5, 8, true><<<dim3(32, 8, 1), 256, 0, stream>>>(Apack, 2048, Wv, outB_p, Wv, outB_p, 2048);
  k_sum_outB<<<640, 256, 0, stream>>>(outB_p, outB);
  // O projection
  gemm_bt<5, 8, false><<<dim3(32, 8, 1), 256, 0, stream>>>(outB, 2048, Wo, ext_p, Wo, ext_p, 2048);
  k_rms<<<96, 256, 0, stream>>>(ext_p, ln_w, extracted, xnb);
  k_vi_pack<<<256, 256, 0, stream>>>(extracted, hs, vi);
  // FFN up+gate (batched) and value-MLP layer 1
  gemm_bt<5, 16, false><<<dim3(64, 4, 2), 256, 0, stream>>>(xnb, 2048, Wgate, gate_p, Wup, up_p, 4096);
  gemm_bt<1, 8, false><<<dim3(32, 16, 1), 256, 0, stream>>>(vi, 4096, V1, h1_p, V1, h1_p, 2048);
  k_act<<<1280, 256, 0, stream>>>(gate_p, up_p, hb);
  k_h1act<<<128, 256, 0, stream>>>(h1_p, b1, h1s);
  // FFN down and value-MLP layer 2
  gemm_bt<5, 16, false><<<dim3(32, 8, 1), 256, 0, stream>>>(hb, 4096, Wdown, ffn_p, Wdown, ffn_p, 2048);
  gemm_bt<1, 8, false><<<dim3(8, 8, 1), 256, 0, stream>>>(h1s, 2048, V2, h2_p, V2, h2_p, 512);
  // outputs
  k_memory<<<512, 256, 0, stream>>>(extracted, ffn_p, out);
  k_heads<<<72, 256, 0, stream>>>(out, extracted, h2_p, Wp, bp, Wh, bh, b2, V3, b3, out);
  k_scan<<<1, 64, 0, stream>>>(buf_pri, out, out, tw);
  k_entries<<<128, 256, 0, stream>>>(buf_ent, out, tw, out);
}

// Round 4
// 282.219 us; speedup vs baseline: 1.5596x; 1.1098x over previous
//
#include <hip/hip_runtime.h>

// ---------------- constants ----------------
#define SS    4096
#define HH    2048
#define NQQ   18
#define QH    72
#define SCALE_F 0.044194173824159216f   // 1/sqrt(512)

// output regions (f32 elements)
#define OUT_MEM     0
#define OUT_PRI     131072
#define OUT_CONF    131136
#define OUT_VAL     131140
#define OUT_ENT     131144
#define OUT_NEWPRI  393288

typedef float  f32x4  __attribute__((ext_vector_type(4)));
typedef __bf16 bf16x8 __attribute__((ext_vector_type(8)));

#define DEVFN static __device__ __forceinline__

DEVFN bf16x8 pack8(f32x4 lo, f32x4 hi){
  bf16x8 r;
  #pragma unroll
  for (int i = 0; i < 4; i++){ r[i] = (__bf16)lo[i]; r[i+4] = (__bf16)hi[i]; }
  return r;
}
DEVFN float siluf(float x){ return x / (1.f + expf(-x)); }
DEVFN float block_sum(float v, float* sb){   // 256 threads
  #pragma unroll
  for (int o = 32; o > 0; o >>= 1) v += __shfl_xor(v, o);
  int wid = threadIdx.x >> 6, lane = threadIdx.x & 63;
  if (lane == 0) sb[wid] = v;
  __syncthreads();
  v = sb[0] + sb[1] + sb[2] + sb[3];
  __syncthreads();
  return v;
}

// ======== GEMM-BT: Cp[y][Mp][N] = A_bf16(Mp,Kf) @ B_f32(N,Kf)^T (K-chunk y) ========
// grid (N/64, Kf/(32*KC), Z). Z=2 selects (B1,C1). HSEL: A block by output head (n0>>9).
template<int MF, int KC, bool HSEL>
__global__ __launch_bounds__(256) void gemm_bt(
    const __bf16* __restrict__ A, int Kf,
    const float* __restrict__ B0, float* __restrict__ C0,
    const float* __restrict__ B1, float* __restrict__ C1,
    int N)
{
  constexpr int Mp = 16 * MF;
  const int lane = threadIdx.x & 63, w = threadIdx.x >> 6;
  const int n0 = blockIdx.x * 64 + w * 16;
  const int k0 = blockIdx.y * KC * 32;
  const float* B = blockIdx.z ? B1 : B0;
  float* Cp      = blockIdx.z ? C1 : C0;
  const __bf16* aBase = A + (HSEL ? (long)(n0 >> 9) * Mp * Kf : 0)
                          + (long)(lane & 15) * Kf + k0 + 8 * (lane >> 4);
  const float* bBase = B + (long)(n0 + (lane & 15)) * Kf + k0 + 8 * (lane >> 4);
  f32x4 acc[MF];
  #pragma unroll
  for (int m = 0; m < MF; m++) acc[m] = (f32x4)(0.f);
  #pragma unroll 4
  for (int c = 0; c < KC; c++){
    f32x4 lo = *reinterpret_cast<const f32x4*>(bBase + c * 32);
    f32x4 hi = *reinterpret_cast<const f32x4*>(bBase + c * 32 + 4);
    bf16x8 bb = pack8(lo, hi);
    #pragma unroll
    for (int m = 0; m < MF; m++){
      bf16x8 aa = *reinterpret_cast<const bf16x8*>(aBase + (long)m * 16 * Kf + c * 32);
      acc[m] = __builtin_amdgcn_mfma_f32_16x16x32_bf16(aa, bb, acc[m], 0, 0, 0);
    }
  }
  float* cp = Cp + (long)blockIdx.y * Mp * N;
  int row0 = 4 * (lane >> 4), col = n0 + (lane & 15);
  #pragma unroll
  for (int m = 0; m < MF; m++)
    #pragma unroll
    for (int r = 0; r < 4; r++)
      cp[(long)(m * 16 + row0 + r) * N + col] = acc[m][r];
}

// ======== GEMM-ABNAT: Cp[z][y][Mp][N] = A_bf16(z)(Mp,aStride) @ Bn_f32(z)(K,N) ========
// cBatch MUST equal gridDim.y * Mp * N (z-major slab layout [z][y][Mp][N]).
template<int MF, int KC>
__global__ __launch_bounds__(256) void gemm_abnat(
    const __bf16* __restrict__ A, long aBatch, int aStride,
    const float* __restrict__ Bn, long bBatch,
    float* __restrict__ Cp, long cBatch,
    int N)
{
  constexpr int Mp = 16 * MF;
  const int lane = threadIdx.x & 63, w = threadIdx.x >> 6;
  const int z = blockIdx.z;
  const int n0 = blockIdx.x * 64 + w * 16;
  const int k0 = blockIdx.y * KC * 32;
  const __bf16* aBase = A + z * aBatch + (long)(lane & 15) * aStride + k0 + 8 * (lane >> 4);
  const float* bBase = Bn + z * bBatch + (long)(k0 + 8 * (lane >> 4)) * N + n0 + (lane & 15);
  f32x4 acc[MF];
  #pragma unroll
  for (int m = 0; m < MF; m++) acc[m] = (f32x4)(0.f);
  #pragma unroll 2
  for (int c = 0; c < KC; c++){
    const float* bp = bBase + (long)c * 32 * N;
    bf16x8 bb;
    #pragma unroll
    for (int j = 0; j < 8; j++) bb[j] = (__bf16)bp[(long)j * N];
    #pragma unroll
    for (int m = 0; m < MF; m++){
      bf16x8 aa = *reinterpret_cast<const bf16x8*>(aBase + (long)m * 16 * aStride + c * 32);
      acc[m] = __builtin_amdgcn_mfma_f32_16x16x32_bf16(aa, bb, acc[m], 0, 0, 0);
    }
  }
  float* cp = Cp + z * cBatch + (long)blockIdx.y * Mp * N;
  int row0 = 4 * (lane >> 4), col = n0 + (lane & 15);
  #pragma unroll
  for (int m = 0; m < MF; m++)
    #pragma unroll
    for (int r = 0; r < 4; r++)
      cp[(long)(m * 16 + row0 + r) * N + col] = acc[m][r];
}

// ======== pass1: Sp[y][b][qh][s] = hs(b)(s,H) @ qk_bf16(80,H)^T, transposed store ========
template<int KC>
__global__ __launch_bounds__(256) void gemm_pass1(
    const float* __restrict__ hs, const __bf16* __restrict__ qk,
    float* __restrict__ Sp)
{
  const int lane = threadIdx.x & 63, w = threadIdx.x >> 6;
  const int b = blockIdx.z;
  const int s0 = blockIdx.x * 64 + w * 16;
  const int k0 = blockIdx.y * KC * 32;
  const float* aBase = hs + ((long)b * SS + s0 + (lane & 15)) * HH + k0 + 8 * (lane >> 4);
  const __bf16* bBase = qk + (long)(lane & 15) * HH + k0 + 8 * (lane >> 4);
  f32x4 acc[5];
  #pragma unroll
  for (int n = 0; n < 5; n++) acc[n] = (f32x4)(0.f);
  #pragma unroll 4
  for (int c = 0; c < KC; c++){
    f32x4 lo = *reinterpret_cast<const f32x4*>(aBase + c * 32);
    f32x4 hi = *reinterpret_cast<const f32x4*>(aBase + c * 32 + 4);
    bf16x8 aa = pack8(lo, hi);
    #pragma unroll
    for (int n = 0; n < 5; n++){
      bf16x8 bb = *reinterpret_cast<const bf16x8*>(bBase + (long)n * 16 * HH + c * 32);
      acc[n] = __builtin_amdgcn_mfma_f32_16x16x32_bf16(aa, bb, acc[n], 0, 0, 0);
    }
  }
  float* sp = Sp + ((long)blockIdx.y * 4 + b) * 80 * SS;
  int scol = s0 + 4 * (lane >> 4);
  #pragma unroll
  for (int n = 0; n < 5; n++){
    int qh = n * 16 + (lane & 15);
    *reinterpret_cast<f32x4*>(sp + (long)qh * SS + scol) = acc[n];
  }
}

// ---------------- small / epilogue kernels ----------------
__global__ void k_prep_qA(const float* __restrict__ queries, __bf16* __restrict__ qA){
  int i = blockIdx.x * 256 + threadIdx.x;       // 32*2048
  int r = i >> 11;
  qA[i] = (__bf16)((r < NQQ) ? queries[i] : 0.f);
}
__global__ void k_mkQ2(const float* __restrict__ q_p, __bf16* __restrict__ Q2){
  int i = blockIdx.x * 256 + threadIdx.x;       // 80*2048
  int qh = i >> 11, e = i & 2047;
  float v = 0.f;
  if (qh < QH){
    int h = qh / NQQ, qq = qh - h * NQQ;
    if ((e >> 9) == h){
      float s = 0.f;
      #pragma unroll
      for (int y = 0; y < 16; y++) s += q_p[(long)y * 32 * 2048 + qq * 2048 + e];
      v = s * SCALE_F;
    }
  }
  Q2[i] = (__bf16)v;
}
__global__ void k_mkqk(const float* __restrict__ qk_p, __bf16* __restrict__ qk_bf){
  int i = blockIdx.x * 256 + threadIdx.x;       // 80*2048
  float s = 0.f;
  #pragma unroll
  for (int y = 0; y < 16; y++) s += qk_p[(long)y * 80 * 2048 + i];
  qk_bf[i] = (__bf16)s;
}
__global__ __launch_bounds__(256) void k_softmax(const float* __restrict__ Sp, __bf16* __restrict__ attn){
  int qh = blockIdx.x, b = blockIdx.y;
  __bf16* arow = attn + ((long)b * 80 + qh) * SS;
  if (qh >= QH){
    #pragma unroll
    for (int it = 0; it < 16; it++) arow[threadIdx.x + 256 * it] = (__bf16)0.f;
    return;
  }
  const float* r0 = Sp + ((long)b * 80 + qh) * SS;
  const long ys = (long)4 * 80 * SS;
  float x[16]; float mx = -1e30f;
  #pragma unroll
  for (int it = 0; it < 16; it++){
    int s = threadIdx.x + 256 * it;
    x[it] = (r0[s] + r0[s + ys]) + (r0[s + 2 * ys] + r0[s + 3 * ys]);
    mx = fmaxf(mx, x[it]);
  }
  __shared__ float sb[8];
  #pragma unroll
  for (int o = 32; o > 0; o >>= 1) mx = fmaxf(mx, __shfl_xor(mx, o));
  int wid = threadIdx.x >> 6, lane = threadIdx.x & 63;
  if (lane == 0) sb[wid] = mx;
  __syncthreads();
  mx = fmaxf(fmaxf(sb[0], sb[1]), fmaxf(sb[2], sb[3]));
  float sum = 0.f;
  #pragma unroll
  for (int it = 0; it < 16; it++){ x[it] = expf(x[it] - mx); sum += x[it]; }
  #pragma unroll
  for (int o = 32; o > 0; o >>= 1) sum += __shfl_xor(sum, o);
  if (lane == 0) sb[4 + wid] = sum;
  __syncthreads();
  sum = sb[4] + sb[5] + sb[6] + sb[7];
  float inv = 1.f / sum;
  #pragma unroll
  for (int it = 0; it < 16; it++) arow[threadIdx.x + 256 * it] = (__bf16)(x[it] * inv);
}
// w_p layout [b][y][80][2048], y in [0,8)
__global__ void k_pack_wv(const float* __restrict__ w_p, __bf16* __restrict__ Apack){
  int i = blockIdx.x * 256 + threadIdx.x;       // 4*80*2048
  int h = i / (80 * 2048);
  int r = (i / 2048) % 80;
  int e = i & 2047;
  float v = 0.f;
  if (r < QH){
    int b = r / NQQ, qq = r - b * NQQ;
    const float* base = w_p + ((long)b * 8 * 80 + (h * NQQ + qq)) * 2048 + e;
    #pragma unroll
    for (int y = 0; y < 8; y++) v += base[(long)y * 80 * 2048];
  }
  Apack[i] = (__bf16)v;
}
__global__ void k_sum_outB(const float* __restrict__ outB_p, __bf16* __restrict__ outB){
  int i = blockIdx.x * 256 + threadIdx.x;       // 80*2048
  float s = 0.f;
  #pragma unroll
  for (int y = 0; y < 16; y++) s += outB_p[(long)y * 80 * 2048 + i];
  outB[i] = (__bf16)s;
}
// rms + extracted materialization + vi packing fused. grid 96.
__global__ __launch_bounds__(256) void k_rms(const float* __restrict__ ext_p, const float* __restrict__ ln_w,
                                             const float* __restrict__ hs,
                                             float* __restrict__ extracted, __bf16* __restrict__ xnb,
                                             __bf16* __restrict__ vi){
  int r = blockIdx.x;
  if (r >= 80){
    if (r < 84){                                 // vi[b][2048..4096] = hs[b, S-1, :]
      int b = r - 80;
      const float* src = hs + ((long)b * SS + (SS - 1)) * HH;
      #pragma unroll
      for (int it = 0; it < 8; it++){
        int e = threadIdx.x + 256 * it;
        vi[(long)b * 4096 + 2048 + e] = (__bf16)src[e];
      }
    } else {                                     // zero vi rows 4..15
      int row = 4 + (r - 84);
      #pragma unroll
      for (int it = 0; it < 16; it++)
        vi[(long)row * 4096 + threadIdx.x + 256 * it] = (__bf16)0.f;
    }
    return;
  }
  float xv[8]; float ss = 0.f;
  #pragma unroll
  for (int it = 0; it < 8; it++){
    int e = threadIdx.x + 256 * it;
    float s = 0.f;
    #pragma unroll
    for (int y = 0; y < 16; y++) s += ext_p[((long)y * 80 + r) * 2048 + e];
    extracted[(long)r * 2048 + e] = s;
    xv[it] = s;
    ss += s * s;
  }
  if (r >= QH) return;
  int b = r / NQQ, qq = r - b * NQQ;
  if (qq < 16){
    __shared__ float sb[4];
    ss = block_sum(ss, sb);
    float inv = 1.f / sqrtf(ss * (1.f / 2048.f) + 1e-6f);
    __bf16* dst = xnb + (long)(b * 16 + qq) * HH;
    #pragma unroll
    for (int it = 0; it < 8; it++){
      int e = threadIdx.x + 256 * it;
      dst[e] = (__bf16)(xv[it] * inv * ln_w[e]);
    }
  } else if (qq == 17){                          // vi[b][0..2048] = extracted row
    #pragma unroll
    for (int it = 0; it < 8; it++){
      int e = threadIdx.x + 256 * it;
      vi[(long)b * 4096 + e] = (__bf16)xv[it];
    }
  }
}
__global__ void k_act(const float* __restrict__ gate_p, const float* __restrict__ up_p,
                      __bf16* __restrict__ hb){
  int i = blockIdx.x * 256 + threadIdx.x;       // 64*4096
  float g = 0.f, u = 0.f;
  #pragma unroll
  for (int y = 0; y < 4; y++){
    g += gate_p[(long)y * 64 * 4096 + i];
    u += up_p[(long)y * 64 * 4096 + i];
  }
  hb[i] = (__bf16)(siluf(g) * u);
}
__global__ void k_h1act(const float* __restrict__ h1_p, const float* __restrict__ b1,
                        __bf16* __restrict__ h1s){
  int i = blockIdx.x * 256 + threadIdx.x;       // 16*2048
  int r = i >> 11, e = i & 2047;
  float v = 0.f;
  if (r < 4){
    float s = 0.f;
    #pragma unroll
    for (int y = 0; y < 16; y++) s += h1_p[(long)y * 16 * 2048 + i];
    v = siluf(s + b1[e]);
  }
  h1s[i] = (__bf16)v;
}
// memory + priority + confidence + value, one kernel. grid 72.
__global__ __launch_bounds__(256) void k_epilogue(
    const float* __restrict__ extracted, const float* __restrict__ ffn_p,
    const float* __restrict__ h2_p,
    const float* __restrict__ Wp, const float* __restrict__ bp,
    const float* __restrict__ Wh, const float* __restrict__ bh,
    const float* __restrict__ b2, const float* __restrict__ V3, const float* __restrict__ b3,
    float* __restrict__ out)
{
  __shared__ float sb[4];
  int blk = blockIdx.x;
  if (blk < 64){                                 // memory row + priority
    int b = blk >> 4, qq = blk & 15;
    const float* ext = extracted + (long)(b * NQQ + qq) * HH;
    float pv = 0.f;
    #pragma unroll
    for (int it = 0; it < 8; it++){
      int e = threadIdx.x + 256 * it;
      float f = 0.f;
      #pragma unroll
      for (int y = 0; y < 8; y++) f += ffn_p[((long)y * 64 + blk) * 2048 + e];
      float m = ext[e] + f;
      out[OUT_MEM + (long)blk * 2048 + e] = m;
      pv += m * Wp[e];
    }
    pv = block_sum(pv, sb);
    if (threadIdx.x == 0) out[OUT_PRI + blk] = 1.f / (1.f + expf(-(pv + bp[0])));
  } else if (blk < 68){                          // confidence
    int b = blk - 64;
    const float* m = extracted + (long)(b * NQQ + 16) * HH;
    float v = 0.f;
    #pragma unroll
    for (int it = 0; it < 8; it++){ int e = threadIdx.x + 256 * it; v += m[e] * Wh[e]; }
    v = block_sum(v, sb);
    if (threadIdx.x == 0) out[OUT_CONF + b] = 1.f / (1.f + expf(-(v + bh[0])));
  } else {                                       // value
    int b = blk - 68;
    float v = 0.f;
    #pragma unroll
    for (int it = 0; it < 2; it++){
      int j = threadIdx.x + 256 * it;
      float s = 0.f;
      #pragma unroll
      for (int y = 0; y < 16; y++) s += h2_p[(long)y * 16 * 512 + b * 512 + j];
      v += siluf(s + b2[j]) * V3[j];
    }
    v = block_sum(v, sb);
    if (threadIdx.x == 0) out[OUT_VAL + b] = v + b3[0];
  }
}
__global__ void k_scan(const float* __restrict__ buf_pri, const float* __restrict__ out_ro,
                       float* __restrict__ out, int* __restrict__ tw){
  int lane = threadIdx.x;                        // 64 threads
  float pr0 = buf_pri[lane], pr1 = buf_pri[lane + 64];
  int tw0 = -1, tw1 = -1;
  for (int i = 0; i < 16; i++){
    float p = out_ro[OUT_PRI + i];
    float v; int idx;
    if (pr0 <= pr1){ v = pr0; idx = lane; } else { v = pr1; idx = lane + 64; }
    #pragma unroll
    for (int o = 32; o > 0; o >>= 1){
      float ov = __shfl_xor(v, o);
      int   oi = __shfl_xor(idx, o);
      if (ov < v || (ov == v && oi < idx)){ v = ov; idx = oi; }
    }
    if (p > v){
      if (idx == lane)          { pr0 = p; tw0 = i; }
      else if (idx == lane + 64){ pr1 = p; tw1 = i; }
    }
  }
  out[OUT_NEWPRI + lane]      = pr0;
  out[OUT_NEWPRI + lane + 64] = pr1;
  tw[lane] = tw0; tw[lane + 64] = tw1;
}
__global__ void k_entries(const float* __restrict__ buf_ent, const float* __restrict__ out_ro,
                          const int* __restrict__ tw, float* __restrict__ out){
  int row = blockIdx.x;                          // 0..127
  int t = tw[row];
  const f32x4* s = reinterpret_cast<const f32x4*>(
      (t < 0) ? (buf_ent + (long)row * HH) : (out_ro + OUT_MEM + (long)t * HH));
  f32x4* d = reinterpret_cast<f32x4*>(out + OUT_ENT + (long)row * HH);
  #pragma unroll
  for (int i = 0; i < 2; i++) d[threadIdx.x + 256 * i] = s[threadIdx.x + 256 * i];
}

// ---------------- launcher ----------------
extern "C" void kernel_launch(void* const* d_in, const int* in_sizes, int n_in,
                              void* d_out, int out_size, void* d_ws, size_t ws_size,
                              hipStream_t stream)
{
  const float* hs      = (const float*)d_in[0];
  const float* buf_ent = (const float*)d_in[1];
  const float* buf_pri = (const float*)d_in[2];
  const float* queries = (const float*)d_in[3];
  const float* Wq  = (const float*)d_in[4];
  const float* Wk  = (const float*)d_in[5];
  const float* Wv  = (const float*)d_in[6];
  const float* Wo  = (const float*)d_in[7];
  const float* ln_w= (const float*)d_in[8];
  const float* Wgate=(const float*)d_in[9];
  const float* Wup = (const float*)d_in[10];
  const float* Wdown=(const float*)d_in[11];
  const float* Wp  = (const float*)d_in[12];
  const float* bp  = (const float*)d_in[13];
  const float* Wh  = (const float*)d_in[14];
  const float* bh  = (const float*)d_in[15];
  const float* V1  = (const float*)d_in[16];
  const float* b1  = (const float*)d_in[17];
  const float* V2  = (const float*)d_in[18];
  const float* b2  = (const float*)d_in[19];
  const float* V3  = (const float*)d_in[20];
  const float* b3  = (const float*)d_in[21];
  float* out = (float*)d_out;
  char* ws = (char*)d_ws;

  // ---- RegionA (20 MB, time-aliased; no memset, no atomics) ----
  float* q_p      = (float*)(ws + 0);            // [16][32][2048]
  float* qk_p     = (float*)(ws + 0);            // [16][80][2048]
  float* scores_p = (float*)(ws + 0);            // [4][4][80][4096]
  float* w_p      = (float*)(ws + 0);            // [4][8][80][2048]  (b-major, 8 K-slabs)
  float* outB_p   = (float*)(ws + 0);            // [16][80][2048]
  float* ext_p    = (float*)(ws + 0);            // [16][80][2048]
  float* gate_p   = (float*)(ws + 0);            // [4][64][4096]
  float* up_p     = (float*)(ws + 4194304);      // [4][64][4096]
  float* ffn_p    = (float*)(ws + 0);            // [8][64][2048]
  // ---- persistents (from 20,971,520) ----
  __bf16* qA    = (__bf16*)(ws + 20971520);      // 32*2048
  __bf16* Q2    = (__bf16*)(ws + 21102592);      // 80*2048
  __bf16* qk_bf = (__bf16*)(ws + 21430272);      // 80*2048
  __bf16* attn  = (__bf16*)(ws + 21757952);      // 4*80*4096
  __bf16* Apack = (__bf16*)(ws + 24379392);      // 4*80*2048
  __bf16* outB  = (__bf16*)(ws + 25690112);      // 80*2048
  float*  extracted = (float*)(ws + 26017792);   // 80*2048 f32
  __bf16* xnb   = (__bf16*)(ws + 26673152);      // 64*2048
  __bf16* hb    = (__bf16*)(ws + 26935296);      // 64*4096
  __bf16* vi    = (__bf16*)(ws + 27459584);      // 16*4096
  __bf16* h1s   = (__bf16*)(ws + 27590656);      // 16*2048
  float*  h1_p  = (float*)(ws + 27656192);       // [16][16][2048]
  float*  h2_p  = (float*)(ws + 29753344);       // [16][16][512]
  int*    tw    = (int*)  (ws + 30277632);       // 128

  // q = queries @ Wq^T
  k_prep_qA<<<256, 256, 0, stream>>>(queries, qA);
  gemm_bt<2, 4, false><<<dim3(32, 16, 1), 256, 0, stream>>>(qA, 2048, Wq, q_p, Wq, q_p, 2048);
  k_mkQ2<<<640, 256, 0, stream>>>(q_p, Q2);
  // qk = Q2 @ Wk
  gemm_abnat<5, 4><<<dim3(32, 16, 1), 256, 0, stream>>>(Q2, 0, 2048, Wk, 0, qk_p, 0, 2048);
  k_mkqk<<<640, 256, 0, stream>>>(qk_p, qk_bf);
  // pass1: scores_t[y][b][qh][s] = hs @ qk^T
  gemm_pass1<16><<<dim3(64, 4, 4), 256, 0, stream>>>(hs, qk_bf, scores_p);
  k_softmax<<<dim3(80, 4), 256, 0, stream>>>(scores_p, attn);
  // pass3: weighted = attn @ hs  (cBatch = gridDim.y * 80 * 2048, z-major)
  gemm_abnat<5, 16><<<dim3(32, 8, 4), 256, 0, stream>>>(attn, 80L * 4096, 4096,
      hs, (long)SS * HH, w_p, 8L * 80 * 2048, 2048);
  k_pack_wv<<<2560, 256, 0, stream>>>(w_p, Apack);
  // V projection (block-diag by head), output already in outB layout
  gemm_bt<5, 4, true><<<dim3(32, 16, 1), 256, 0, stream>>>(Apack, 2048, Wv, outB_p, Wv, outB_p, 2048);
  k_sum_outB<<<640, 256, 0, stream>>>(outB_p, outB);
  // O projection
  gemm_bt<5, 4, false><<<dim3(32, 16, 1), 256, 0, stream>>>(outB, 2048, Wo, ext_p, Wo, ext_p, 2048);
  k_rms<<<96, 256, 0, stream>>>(ext_p, ln_w, hs, extracted, xnb, vi);
  // FFN up+gate (batched, 64 rows) and value-MLP layer 1
  gemm_bt<4, 16, false><<<dim3(64, 4, 2), 256, 0, stream>>>(xnb, 2048, Wgate, gate_p, Wup, up_p, 4096);
  gemm_bt<1, 8, false><<<dim3(32, 16, 1), 256, 0, stream>>>(vi, 4096, V1, h1_p, V1, h1_p, 2048);
  k_act<<<1024, 256, 0, stream>>>(gate_p, up_p, hb);
  k_h1act<<<128, 256, 0, stream>>>(h1_p, b1, h1s);
  // FFN down and value-MLP layer 2
  gemm_bt<4, 16, false><<<dim3(32, 8, 1), 256, 0, stream>>>(hb, 4096, Wdown, ffn_p, Wdown, ffn_p, 2048);
  gemm_bt<1, 4, false><<<dim3(8, 16, 1), 256, 0, stream>>>(h1s, 2048, V2, h2_p, V2, h2_p, 512);
  // outputs
  k_epilogue<<<72, 256, 0, stream>>>(extracted, ffn_p, h2_p, Wp, bp, Wh, bh, b2, V3, b3, out);
  k_scan<<<1, 64, 0, stream>>>(buf_pri, out, out, tw);
  k_entries<<<128, 256, 0, stream>>>(buf_ent, out, tw, out);
}